// Round 1
// baseline (529.338 us; speedup 1.0000x reference)
//
#include <hip/hip_runtime.h>

// AttentionBasedNN: 4-layer additive (Bahdanau) attention + residual FCs + head.
// VEC=1280, HID=128, B=4, S=256. All fp32 (no fp32 MFMA on CDNA4 -> vector ALU).

#define DEV __device__ __forceinline__

static constexpr int VEC = 1280;
static constexpr int HID = 128;
static constexpr int BB  = 4;
static constexpr int SS  = 256;
static constexpr int MROWS = BB * SS;   // 1024

DEV float ftanh(float x) {
  // tanh(x) = 1 - 2/(exp(2x)+1); exp->inf gives +1, exp->0 gives -1. ~1e-6 abs err.
  float e = __expf(2.0f * x);
  return 1.0f - __fdividef(2.0f, e + 1.0f);
}

DEV float waveSum(float v) {
#pragma unroll
  for (int off = 32; off > 0; off >>= 1) v += __shfl_xor(v, off, 64);
  return v;
}
DEV float waveMax(float v) {
#pragma unroll
  for (int off = 32; off > 0; off >>= 1) v = fmaxf(v, __shfl_xor(v, off, 64));
  return v;
}
// blockDim.x == 256 (4 waves) everywhere these are used.
DEV float blockSum(float v, float* red) {
  v = waveSum(v);
  int tid = threadIdx.x;
  if ((tid & 63) == 0) red[tid >> 6] = v;
  __syncthreads();
  float r = (red[0] + red[1]) + (red[2] + red[3]);
  __syncthreads();
  return r;
}
DEV float blockMax(float v, float* red) {
  v = waveMax(v);
  int tid = threadIdx.x;
  if ((tid & 63) == 0) red[tid >> 6] = v;
  __syncthreads();
  float r = fmaxf(fmaxf(red[0], red[1]), fmaxf(red[2], red[3]));
  __syncthreads();
  return r;
}

// ---------------------------------------------------------------------------
// Generic fp32 GEMM, 64x64 tile, BK=16, 256 threads, 4x4 microtile.
// ZMODE==0: blockIdx.z = batch (strides sAb/sBb/sCb), plain store w/ optional
//           bias/residual epilogue and optional relu(A+aBias) on the A load.
// ZMODE==1: blockIdx.z = K-split index (kChunk each), atomicAdd epilogue
//           (C must be pre-zeroed).
// Dual-B: column n < nSplitB reads B0, else B1 at column n-nSplitB (both ldB).
// ---------------------------------------------------------------------------
template <int ZMODE, bool ABRELU, bool OBIAS, bool ORES>
__global__ __launch_bounds__(256) void gemm_k(
    const float* __restrict__ A, long sAb,
    const float* __restrict__ B0, const float* __restrict__ B1, int nSplitB,
    long sBb, int ldB,
    float* __restrict__ C, long sCb,
    const float* __restrict__ aBias, const float* __restrict__ oBias,
    const float* __restrict__ res,
    int N, int K, int kChunk) {
  const int n0 = blockIdx.x * 64;
  const int m0 = blockIdx.y * 64;
  const int z  = blockIdx.z;

  const float* Ab = A + (ZMODE == 0 ? (long)z * sAb : 0L);
  float*       Cb = C + (ZMODE == 0 ? (long)z * sCb : 0L);
  const float* Bsel;
  int nb;
  if (n0 < nSplitB) { Bsel = B0; nb = n0; } else { Bsel = B1; nb = n0 - nSplitB; }
  Bsel += (ZMODE == 0 ? (long)z * sBb : 0L);

  const int kBeg = (ZMODE == 1) ? z * kChunk : 0;
  const int kEnd = (ZMODE == 1) ? kBeg + kChunk : K;

  __shared__ float As[16][68];  // [k][m], pad 68 for bank spread, 16B aligned rows
  __shared__ float Bs[16][68];  // [k][n]

  const int tid = threadIdx.x;
  const int tx = tid & 15, ty = tid >> 4;
  const int ar = tid >> 2, ac = (tid & 3) << 2;   // A tile: row 0..63, k-col {0,4,8,12}
  const int br = tid >> 4, bc = (tid & 15) << 2;  // B tile: k-row 0..15, col 0..60

  float acc[4][4] = {};

  for (int kt = kBeg; kt < kEnd; kt += 16) {
    float4 a4 = *(const float4*)(Ab + (size_t)(m0 + ar) * K + kt + ac);
    float4 b4 = *(const float4*)(Bsel + (size_t)(kt + br) * ldB + nb + bc);
    if (ABRELU) {
      float4 bz = *(const float4*)(aBias + kt + ac);
      a4.x = fmaxf(a4.x + bz.x, 0.0f);
      a4.y = fmaxf(a4.y + bz.y, 0.0f);
      a4.z = fmaxf(a4.z + bz.z, 0.0f);
      a4.w = fmaxf(a4.w + bz.w, 0.0f);
    }
    __syncthreads();
    As[ac + 0][ar] = a4.x;
    As[ac + 1][ar] = a4.y;
    As[ac + 2][ar] = a4.z;
    As[ac + 3][ar] = a4.w;
    *(float4*)&Bs[br][bc] = b4;
    __syncthreads();
#pragma unroll
    for (int kk = 0; kk < 16; ++kk) {
      const float4 av = *(const float4*)&As[kk][ty << 2];
      const float4 bv = *(const float4*)&Bs[kk][tx << 2];
      const float a[4] = {av.x, av.y, av.z, av.w};
      const float b[4] = {bv.x, bv.y, bv.z, bv.w};
#pragma unroll
      for (int i = 0; i < 4; ++i)
#pragma unroll
        for (int j = 0; j < 4; ++j) acc[i][j] = fmaf(a[i], b[j], acc[i][j]);
    }
  }

#pragma unroll
  for (int i = 0; i < 4; ++i) {
    const int m = m0 + (ty << 2) + i;
#pragma unroll
    for (int j = 0; j < 4; ++j) {
      const int n = n0 + (tx << 2) + j;
      float v = acc[i][j];
      if (ZMODE == 1) {
        atomicAdd(&Cb[(size_t)m * N + n], v);
      } else {
        if (OBIAS) v += oBias[n];
        if (ORES) v += res[(size_t)m * N + n];
        Cb[(size_t)m * N + n] = v;
      }
    }
  }
}

// ---------------------------------------------------------------------------
// Scores + softmax for layers 1-3. Block = (i, b); thread j in [0,256).
// QK layout: row r=b*256+i, cols [0,128)=Q, [128,256)=K.
// ---------------------------------------------------------------------------
__global__ __launch_bounds__(256) void scores_k(const float* __restrict__ QK,
                                                const float* __restrict__ wv,
                                                float* __restrict__ attn) {
  const int i = blockIdx.x, b = blockIdx.y;
  const int tid = threadIdx.x;
  __shared__ float qs[128], wvs[128];
  __shared__ float red[4];
  if (tid < 128) {
    qs[tid] = QK[((size_t)(b * 256 + i)) * 256 + tid];
    wvs[tid] = wv[tid];
  }
  __syncthreads();
  const float* Kr = QK + ((size_t)(b * 256 + tid)) * 256 + 128;
  float s = 0.0f;
#pragma unroll 8
  for (int h = 0; h < 128; h += 4) {
    float4 k4 = *(const float4*)(Kr + h);
    s += wvs[h + 0] * ftanh(qs[h + 0] + k4.x);
    s += wvs[h + 1] * ftanh(qs[h + 1] + k4.y);
    s += wvs[h + 2] * ftanh(qs[h + 2] + k4.z);
    s += wvs[h + 3] * ftanh(qs[h + 3] + k4.w);
  }
  const float mx = blockMax(s, red);
  const float e = __expf(s - mx);
  const float tot = blockSum(e, red);
  attn[((size_t)(b * 256 + i)) * 256 + tid] = e / tot;
}

// LN over rows of (A + Xin): 1024 blocks, 256 threads, 5 elems/thread.
__global__ __launch_bounds__(256) void ln_k(const float* __restrict__ A,
                                            const float* __restrict__ Xin,
                                            float* __restrict__ Y) {
  __shared__ float red[4];
  const int r = blockIdx.x, tid = threadIdx.x;
  const float* a = A + (size_t)r * VEC;
  const float* x = Xin + (size_t)r * VEC;
  float v[5];
  float sum = 0.0f;
#pragma unroll
  for (int k = 0; k < 5; ++k) {
    const int d = tid + k * 256;
    v[k] = a[d] + x[d];
    sum += v[k];
  }
  sum = blockSum(sum, red);
  const float m = sum * (1.0f / VEC);
  float sq = 0.0f;
#pragma unroll
  for (int k = 0; k < 5; ++k) {
    const float dl = v[k] - m;
    sq += dl * dl;
  }
  sq = blockSum(sq, red);
  const float rstd = rsqrtf(sq * (1.0f / VEC) + 1e-5f);
  float* y = Y + (size_t)r * VEC;
#pragma unroll
  for (int k = 0; k < 5; ++k) y[tid + k * 256] = (v[k] - m) * rstd;
}

// Layer-4 scores+softmax: 4 blocks (b), thread j. Query row = lys[0].
__global__ __launch_bounds__(256) void scores4_k(const float* __restrict__ QK,
                                                 const float* __restrict__ wv,
                                                 const int* __restrict__ lys,
                                                 float* __restrict__ attn4) {
  const int b = blockIdx.x, tid = threadIdx.x;
  __shared__ float qs[128], wvs[128];
  __shared__ float red[4];
  const int lp = lys[0];
  if (tid < 128) {
    qs[tid] = QK[((size_t)(b * 256 + lp)) * 256 + tid];
    wvs[tid] = wv[tid];
  }
  __syncthreads();
  const float* Kr = QK + ((size_t)(b * 256 + tid)) * 256 + 128;
  float s = 0.0f;
#pragma unroll 8
  for (int h = 0; h < 128; h += 4) {
    float4 k4 = *(const float4*)(Kr + h);
    s += wvs[h + 0] * ftanh(qs[h + 0] + k4.x);
    s += wvs[h + 1] * ftanh(qs[h + 1] + k4.y);
    s += wvs[h + 2] * ftanh(qs[h + 2] + k4.z);
    s += wvs[h + 3] * ftanh(qs[h + 3] + k4.w);
  }
  const float mx = blockMax(s, red);
  const float e = __expf(s - mx);
  const float tot = blockSum(e, red);
  attn4[b * 256 + tid] = e / tot;
}

// A4 = attn4 @ X3 (per b), residual add X3[b,lys,:], LN -> Xlys[b,:].
__global__ __launch_bounds__(256) void attn4_out_ln_k(const float* __restrict__ attn4,
                                                      const float* __restrict__ X3,
                                                      const int* __restrict__ lys,
                                                      float* __restrict__ Xlys) {
  const int b = blockIdx.x, tid = threadIdx.x;
  __shared__ float aw[256];
  __shared__ float red[4];
  aw[tid] = attn4[b * 256 + tid];
  __syncthreads();
  float acc[5] = {0, 0, 0, 0, 0};
  const float* Xb = X3 + (size_t)b * SS * VEC;
  for (int j = 0; j < 256; ++j) {
    const float a = aw[j];
    const float* xr = Xb + (size_t)j * VEC;
#pragma unroll
    for (int k = 0; k < 5; ++k) acc[k] = fmaf(a, xr[tid + k * 256], acc[k]);
  }
  const int lp = lys[0];
  const float* xq = Xb + (size_t)lp * VEC;
  float sum = 0.0f;
#pragma unroll
  for (int k = 0; k < 5; ++k) {
    acc[k] += xq[tid + k * 256];
    sum += acc[k];
  }
  sum = blockSum(sum, red);
  const float m = sum * (1.0f / VEC);
  float sq = 0.0f;
#pragma unroll
  for (int k = 0; k < 5; ++k) {
    const float dl = acc[k] - m;
    sq += dl * dl;
  }
  sq = blockSum(sq, red);
  const float rstd = rsqrtf(sq * (1.0f / VEC) + 1e-5f);
#pragma unroll
  for (int k = 0; k < 5; ++k) Xlys[b * VEC + tid + k * 256] = (acc[k] - m) * rstd;
}

// Head MLP: 1280 -> 32 (relu) -> 12 (relu) -> 2. One block per b.
__global__ __launch_bounds__(256) void head_k(const float* __restrict__ Xlys,
                                              const float* __restrict__ hW1,
                                              const float* __restrict__ hb1,
                                              const float* __restrict__ hW2,
                                              const float* __restrict__ hb2,
                                              const float* __restrict__ hW3,
                                              const float* __restrict__ hb3,
                                              float* __restrict__ out) {
  const int b = blockIdx.x, tid = threadIdx.x;
  __shared__ float xr[1280];
  __shared__ float partial[256];
  __shared__ float h1s[32], h2s[12];
  for (int k = tid; k < 1280; k += 256) xr[k] = Xlys[b * VEC + k];
  __syncthreads();
  const int n = tid & 31, s = tid >> 5;  // 8 K-slices of 160 per output
  float p = 0.0f;
  for (int k = s * 160; k < s * 160 + 160; ++k) p = fmaf(xr[k], hW1[k * 32 + n], p);
  partial[tid] = p;
  __syncthreads();
  if (tid < 32) {
    float v = 0.0f;
#pragma unroll
    for (int s2 = 0; s2 < 8; ++s2) v += partial[s2 * 32 + tid];
    h1s[tid] = fmaxf(v + hb1[tid], 0.0f);
  }
  __syncthreads();
  if (tid < 12) {
    float v = 0.0f;
#pragma unroll
    for (int k = 0; k < 32; ++k) v = fmaf(h1s[k], hW2[k * 12 + tid], v);
    h2s[tid] = fmaxf(v + hb2[tid], 0.0f);
  }
  __syncthreads();
  if (tid < 2) {
    float v = 0.0f;
#pragma unroll
    for (int k = 0; k < 12; ++k) v = fmaf(h2s[k], hW3[k * 2 + tid], v);
    out[b * 2 + tid] = v + hb3[tid];
  }
}

// ---------------------------------------------------------------------------
extern "C" void kernel_launch(void* const* d_in, const int* in_sizes, int n_in,
                              void* d_out, int out_size, void* d_ws, size_t ws_size,
                              hipStream_t stream) {
  const float* X = (const float*)d_in[0];
  const int* lys = (const int*)d_in[1];
  const float* Wq[4] = {(const float*)d_in[2], (const float*)d_in[5],
                        (const float*)d_in[8], (const float*)d_in[11]};
  const float* Wk[4] = {(const float*)d_in[3], (const float*)d_in[6],
                        (const float*)d_in[9], (const float*)d_in[12]};
  const float* wv[4] = {(const float*)d_in[4], (const float*)d_in[7],
                        (const float*)d_in[10], (const float*)d_in[13]};
  const float* rW1[3] = {(const float*)d_in[14], (const float*)d_in[18],
                         (const float*)d_in[22]};
  const float* rb1[3] = {(const float*)d_in[15], (const float*)d_in[19],
                         (const float*)d_in[23]};
  const float* rW2[3] = {(const float*)d_in[16], (const float*)d_in[20],
                         (const float*)d_in[24]};
  const float* rb2[3] = {(const float*)d_in[17], (const float*)d_in[21],
                         (const float*)d_in[25]};
  const float* hW1 = (const float*)d_in[26];
  const float* hb1 = (const float*)d_in[27];
  const float* hW2 = (const float*)d_in[28];
  const float* hb2 = (const float*)d_in[29];
  const float* hW3 = (const float*)d_in[30];
  const float* hb3 = (const float*)d_in[31];
  float* out = (float*)d_out;

  // Workspace layout (floats). Total ~4.59M floats = 18.4 MB.
  float* ws = (float*)d_ws;
  float* QK    = ws;                   // 1024*256
  float* attn  = QK + 262144;          // 1024*256
  float* big0  = attn + 262144;        // 1024*1280
  float* big1  = big0 + 1310720;
  float* big2  = big1 + 1310720;
  float* Hacc  = big2 + 1310720;       // 1024*128
  float* attn4 = Hacc + 131072;        // 4*256
  float* Xlys  = attn4 + 1024;         // 4*1280

  // Buffer rotation: L1: A=big0 Y=big1 O=big0; L2: A=big1 Y=big2 O=big1;
  // L3: A=big0 Y=big2 O=big0.  (Xin of layer l+1 = O of layer l.)
  float* bufA[3] = {big0, big1, big0};
  float* bufY[3] = {big1, big2, big2};
  float* bufO[3] = {big0, big1, big0};

  const int NSPLIT_NONE = 1 << 30;
  const float* Xin = X;

  for (int l = 0; l < 3; ++l) {
    // QK = Xin @ [Wq|Wk]   (split-K=4, atomic)
    hipMemsetAsync(QK, 0, (size_t)MROWS * 256 * sizeof(float), stream);
    gemm_k<1, false, false, false><<<dim3(4, 16, 4), 256, 0, stream>>>(
        Xin, 0, Wq[l], Wk[l], HID, 0, HID, QK, 0, nullptr, nullptr, nullptr,
        256, VEC, 320);
    // scores + softmax
    scores_k<<<dim3(SS, BB), 256, 0, stream>>>(QK, wv[l], attn);
    // A = attn @ Xin  (batched over b)
    gemm_k<0, false, false, false><<<dim3(20, 4, 4), 256, 0, stream>>>(
        attn, (long)SS * SS, Xin, Xin, NSPLIT_NONE, (long)SS * VEC, VEC,
        bufA[l], (long)SS * VEC, nullptr, nullptr, nullptr, VEC, SS, 0);
    // Y = LN(A + Xin)
    ln_k<<<dim3(MROWS), 256, 0, stream>>>(bufA[l], Xin, bufY[l]);
    // Hacc = Y @ rW1   (split-K=8, atomic)
    hipMemsetAsync(Hacc, 0, (size_t)MROWS * HID * sizeof(float), stream);
    gemm_k<1, false, false, false><<<dim3(2, 16, 8), 256, 0, stream>>>(
        bufY[l], 0, rW1[l], rW1[l], NSPLIT_NONE, 0, HID, Hacc, 0, nullptr,
        nullptr, nullptr, HID, VEC, 160);
    // Xout = relu(Hacc + b1) @ rW2 + b2 + Y
    gemm_k<0, true, true, true><<<dim3(20, 16, 1), 256, 0, stream>>>(
        Hacc, 0, rW2[l], rW2[l], NSPLIT_NONE, 0, VEC, bufO[l], 0, rb1[l],
        rb2[l], bufY[l], VEC, HID, 0);
    Xin = bufO[l];
  }

  // Layer 4: QK4 on X3 (computes all Q rows; only row lys used — acceptable waste)
  hipMemsetAsync(QK, 0, (size_t)MROWS * 256 * sizeof(float), stream);
  gemm_k<1, false, false, false><<<dim3(4, 16, 4), 256, 0, stream>>>(
      Xin, 0, Wq[3], Wk[3], HID, 0, HID, QK, 0, nullptr, nullptr, nullptr,
      256, VEC, 320);
  scores4_k<<<dim3(BB), 256, 0, stream>>>(QK, wv[3], lys, attn4);
  attn4_out_ln_k<<<dim3(BB), 256, 0, stream>>>(attn4, Xin, lys, Xlys);
  head_k<<<dim3(BB), 256, 0, stream>>>(Xlys, hW1, hb1, hW2, hb2, hW3, hb3, out);
}